// Round 1
// baseline (15559.052 us; speedup 1.0000x reference)
//
#include <hip/hip_runtime.h>
#include <cmath>

#define EPS 1e-5f

__device__ __forceinline__ int reflect_idx(int p, int S) {
    if (p < 0) p = -p;
    if (p >= S) p = 2 * S - 2 - p;
    return p;
}

// Direct conv, 'same' output size, NCHW.
// Input = concat(src1 [C1 ch], src2 [C2 ch]) at logical size Hout x Wout.
// If upsample: physical input is (Hout/2, Wout/2), nearest (repeat 2x).
// reflect=1: reflect pad at logical size; reflect=0: zero pad.
// act: 0 = none, 1 = tanh.
template<int K>
__global__ void conv_generic(const float* __restrict__ src1, const float* __restrict__ src2,
                             int C1, int C2,
                             const float* __restrict__ w, const float* __restrict__ bias,
                             float* __restrict__ out,
                             int B, int Co, int Hout, int Wout,
                             int pad, int upsample, int reflect, int act)
{
    int idx = blockIdx.x * blockDim.x + threadIdx.x;
    int total = B * Co * Hout * Wout;
    if (idx >= total) return;
    int x  = idx % Wout;
    int y  = (idx / Wout) % Hout;
    int oc = (idx / (Wout * Hout)) % Co;
    int b  = idx / (Wout * Hout * Co);

    int Cin = C1 + C2;
    int Hin = upsample ? (Hout >> 1) : Hout;
    int Win = upsample ? (Wout >> 1) : Wout;

    int iy[K], ix[K];
    bool vy[K], vx[K];
#pragma unroll
    for (int t = 0; t < K; ++t) {
        int p = y - pad + t;
        if (reflect) { p = reflect_idx(p, Hout); vy[t] = true; }
        else vy[t] = (p >= 0) && (p < Hout);
        iy[t] = upsample ? (p >> 1) : p;
        int q = x - pad + t;
        if (reflect) { q = reflect_idx(q, Wout); vx[t] = true; }
        else vx[t] = (q >= 0) && (q < Wout);
        ix[t] = upsample ? (q >> 1) : q;
    }

    float acc = bias[oc];
    const float* wrow = w + (size_t)oc * Cin * K * K;
    for (int c = 0; c < Cin; ++c) {
        const float* src = (c < C1) ? (src1 + ((size_t)(b * C1 + c)) * Hin * Win)
                                    : (src2 + ((size_t)(b * C2 + (c - C1))) * Hin * Win);
        const float* wc = wrow + c * K * K;
#pragma unroll
        for (int t = 0; t < K; ++t) {
            if (!vy[t]) continue;
            const float* row = src + iy[t] * Win;
#pragma unroll
            for (int u = 0; u < K; ++u) {
                if (!vx[u]) continue;
                acc = fmaf(row[ix[u]], wc[t * K + u], acc);
            }
        }
    }
    if (act == 1) acc = tanhf(acc);
    out[idx] = acc;
}

// InstanceNorm over HW per (b,c) slice. One block per (b,c). In-place safe.
// relu: apply max(0, .) after normalize. resid: if non-null, add resid[i] after (no relu on sum).
__global__ void inorm_kernel(const float* __restrict__ in, float* __restrict__ out,
                             const float* __restrict__ resid, int HW, int relu)
{
    int bc = blockIdx.x;
    const float* p = in + (size_t)bc * HW;
    float s = 0.f, q = 0.f;
    for (int i = threadIdx.x; i < HW; i += blockDim.x) {
        float v = p[i]; s += v; q += v * v;
    }
#pragma unroll
    for (int off = 32; off > 0; off >>= 1) {
        s += __shfl_down(s, off);
        q += __shfl_down(q, off);
    }
    __shared__ float ss[4], sq[4];
    __shared__ float mrs[2];
    int lane = threadIdx.x & 63, wv = threadIdx.x >> 6;
    if (lane == 0) { ss[wv] = s; sq[wv] = q; }
    __syncthreads();
    if (threadIdx.x == 0) {
        float S = 0.f, Q = 0.f;
        int nw = blockDim.x >> 6;
        for (int i = 0; i < nw; ++i) { S += ss[i]; Q += sq[i]; }
        float m = S / HW;
        float v = Q / HW - m * m;
        if (v < 0.f) v = 0.f;
        mrs[0] = m; mrs[1] = rsqrtf(v + EPS);
    }
    __syncthreads();
    float m = mrs[0], rs = mrs[1];
    float* o = out + (size_t)bc * HW;
    const float* r = resid ? resid + (size_t)bc * HW : nullptr;
    for (int i = threadIdx.x; i < HW; i += blockDim.x) {
        float v = (p[i] - m) * rs;
        if (relu) v = fmaxf(v, 0.f);
        if (r) v += r[i];
        o[i] = v;
    }
}

// Deformable conv 3x3, pad=1, Cin==Cout==C. One block = C threads, POS x-positions.
// om layout (B,27,H,W): ch 2k = off_y(k), ch 2k+1 = off_x(k), ch 18+k = mask logit.
template<int C, int POS>
__global__ void deform_conv_kernel(const float* __restrict__ x, const float* __restrict__ om,
                                   const float* __restrict__ w, const float* __restrict__ bias,
                                   float* __restrict__ out, int B, int H, int W)
{
    int nxb = W / POS;
    int blk = blockIdx.x;
    int xb = blk % nxb;
    int y  = (blk / nxb) % H;
    int b  = blk / (nxb * H);
    int tid = threadIdx.x;

    __shared__ float val[POS][C * 9];
    __shared__ int   sy0[POS][9], sx0[POS][9];
    __shared__ float sdy[POS][9], sdx[POS][9], smk[POS][9];

    for (int t = tid; t < POS * 9; t += C) {
        int pos = t / 9, k = t % 9;
        int xx = xb * POS + pos;
        size_t base = ((size_t)b * 27) * H * W + (size_t)y * W + xx;
        float offy = om[base + (size_t)(2 * k) * H * W];
        float offx = om[base + (size_t)(2 * k + 1) * H * W];
        float mk   = om[base + (size_t)(18 + k) * H * W];
        mk = 1.f / (1.f + expf(-mk));
        float py = (float)(y - 1 + k / 3) + offy;
        float px = (float)(xx - 1 + k % 3) + offx;
        float fy = floorf(py), fx = floorf(px);
        sy0[pos][k] = (int)fy; sx0[pos][k] = (int)fx;
        sdy[pos][k] = py - fy; sdx[pos][k] = px - fx;
        smk[pos][k] = mk;
    }
    __syncthreads();

    const float* xbase = x + (size_t)b * C * H * W;
    for (int e = tid; e < POS * C * 9; e += C) {
        int k = e % 9;
        int c = (e / 9) % C;
        int pos = e / (9 * C);
        int y0 = sy0[pos][k], x0 = sx0[pos][k];
        float dy = sdy[pos][k], dx = sdx[pos][k], mk = smk[pos][k];
        const float* xc = xbase + (size_t)c * H * W;
        int y1 = y0 + 1, x1 = x0 + 1;
        bool by0 = (y0 >= 0) && (y0 < H), by1 = (y1 >= 0) && (y1 < H);
        bool bx0 = (x0 >= 0) && (x0 < W), bx1 = (x1 >= 0) && (x1 < W);
        float v00 = (by0 && bx0) ? xc[y0 * W + x0] : 0.f;
        float v01 = (by0 && bx1) ? xc[y0 * W + x1] : 0.f;
        float v10 = (by1 && bx0) ? xc[y1 * W + x0] : 0.f;
        float v11 = (by1 && bx1) ? xc[y1 * W + x1] : 0.f;
        float v = v00 * (1.f - dy) * (1.f - dx) + v01 * (1.f - dy) * dx
                + v10 * dy * (1.f - dx) + v11 * dy * dx;
        val[pos][c * 9 + k] = v * mk;
    }
    __syncthreads();

    int o = tid;
    float acc[POS];
#pragma unroll
    for (int p2 = 0; p2 < POS; ++p2) acc[p2] = bias[o];
    const float* wo = w + (size_t)o * C * 9;
    for (int ck = 0; ck < C * 9; ++ck) {
        float wv = wo[ck];
#pragma unroll
        for (int p2 = 0; p2 < POS; ++p2)
            acc[p2] = fmaf(val[p2][ck], wv, acc[p2]);
    }
#pragma unroll
    for (int p2 = 0; p2 < POS; ++p2) {
        int xx = xb * POS + p2;
        out[((size_t)(b * C + o) * H + y) * W + xx] = acc[p2];
    }
}

// Sum |om[:, 0:18, :, :]| into *acc (om has Ctot channels).
__global__ void abs_sum_kernel(const float* __restrict__ om, int B, int Ctot, int HW,
                               float* __restrict__ acc)
{
    long long total = (long long)B * 18 * HW;
    float s = 0.f;
    for (long long i = (long long)blockIdx.x * blockDim.x + threadIdx.x; i < total;
         i += (long long)gridDim.x * blockDim.x) {
        int pos = (int)(i % HW);
        int c   = (int)((i / HW) % 18);
        int b   = (int)(i / ((long long)18 * HW));
        s += fabsf(om[((size_t)(b * Ctot + c)) * HW + pos]);
    }
#pragma unroll
    for (int off = 32; off > 0; off >>= 1) s += __shfl_down(s, off);
    __shared__ float ws_[4];
    int lane = threadIdx.x & 63, wv = threadIdx.x >> 6;
    if (lane == 0) ws_[wv] = s;
    __syncthreads();
    if (threadIdx.x == 0) {
        float t = 0.f;
        int nw = blockDim.x >> 6;
        for (int i = 0; i < nw; ++i) t += ws_[i];
        atomicAdd(acc, t);
    }
}

__global__ void zero2_kernel(float* a) { if (threadIdx.x < 2) a[threadIdx.x] = 0.f; }

__global__ void finalize_kernel(const float* __restrict__ acc, float* __restrict__ out) {
    // acc[0] = sum|offset1| (om1, 128x128), acc[1] = sum|offset2| (om2, 64x64)
    out[0] = 0.5f * (acc[0] / (4.f * 18.f * 128.f * 128.f)
                   + acc[1] / (4.f * 18.f * 64.f * 64.f));
}

extern "C" void kernel_launch(void* const* d_in, const int* in_sizes, int n_in,
                              void* d_out, int out_size, void* d_ws, size_t ws_size,
                              hipStream_t stream)
{
    const float* x      = (const float*)d_in[0];
    const float* skip1  = (const float*)d_in[1];
    const float* skip2  = (const float*)d_in[2];
    const float* res_w  = (const float*)d_in[3];
    const float* res_b  = (const float*)d_in[4];
    const float* w1     = (const float*)d_in[5];
    const float* b1     = (const float*)d_in[6];
    const float* w2     = (const float*)d_in[7];
    const float* b2     = (const float*)d_in[8];
    const float* w3     = (const float*)d_in[9];
    const float* b3     = (const float*)d_in[10];
    const float* off2_w = (const float*)d_in[11];
    const float* off2_b = (const float*)d_in[12];
    const float* dcn2_w = (const float*)d_in[13];
    const float* dcn2_b = (const float*)d_in[14];
    const float* off1_w = (const float*)d_in[15];
    const float* off1_b = (const float*)d_in[16];
    const float* dcn1_w = (const float*)d_in[17];
    const float* dcn1_b = (const float*)d_in[18];

    float* ws = (float*)d_ws;
    // workspace layout (floats)
    float* cur  = ws;              // (4,256,32,32)   1,048,576
    float* hbuf = ws + 1048576;    // (4,256,32,32)   1,048,576
    float* tbuf = ws + 2097152;    // (4,256,32,32)   1,048,576
    float* out1 = ws + 3145728;    // (4,128,64,64)   2,097,152
    float* om2  = ws + 5242880;    // (4,27,64,64)      442,368
    float* pre2 = ws + 5685248;    // (4,128,64,64)   2,097,152
    float* out2 = ws + 7782400;    // (4,64,128,128)  4,194,304
    float* om1  = ws + 11976704;   // (4,27,128,128)  1,769,472
    float* pre1 = ws + 13746176;   // (4,64,128,128)  4,194,304
    float* acc  = ws + 17940480;   // 2 floats
    if (ws_size < (size_t)17940482 * sizeof(float)) return;

    float* outp = (float*)d_out;

    zero2_kernel<<<dim3(1), dim3(64), 0, stream>>>(acc);

    auto nb = [](int n) { return dim3((unsigned)((n + 255) / 256)); };

    // ---- residual blocks (256ch @ 32x32) ----
    for (int i = 0; i < 2; ++i) {
        const float* src = (i == 0) ? x : cur;
        const float* wA = res_w + (size_t)(i * 2 + 0) * 256 * 256 * 9;
        const float* bA = res_b + (i * 2 + 0) * 256;
        const float* wB = res_w + (size_t)(i * 2 + 1) * 256 * 256 * 9;
        const float* bB = res_b + (i * 2 + 1) * 256;
        conv_generic<3><<<nb(4*256*32*32), 256, 0, stream>>>(src, nullptr, 256, 0, wA, bA, tbuf,
                                                             4, 256, 32, 32, 1, 0, 1, 0);
        inorm_kernel<<<dim3(1024), dim3(256), 0, stream>>>(tbuf, hbuf, nullptr, 1024, 1);
        conv_generic<3><<<nb(4*256*32*32), 256, 0, stream>>>(hbuf, nullptr, 256, 0, wB, bB, tbuf,
                                                             4, 256, 32, 32, 1, 0, 1, 0);
        inorm_kernel<<<dim3(1024), dim3(256), 0, stream>>>(tbuf, cur, src, 1024, 0);
    }

    // ---- up2 + refpad2 + conv5x5 (256->128) @64x64, IN+relu ----
    conv_generic<5><<<nb(4*128*64*64), 256, 0, stream>>>(cur, nullptr, 256, 0, w1, b1, out1,
                                                         4, 128, 64, 64, 2, 1, 1, 0);
    inorm_kernel<<<dim3(512), dim3(256), 0, stream>>>(out1, out1, nullptr, 4096, 1);

    // ---- om2 = conv3x3 zero-pad on concat[out1, skip2] (256->27) @64x64 ----
    conv_generic<3><<<nb(4*27*64*64), 256, 0, stream>>>(out1, skip2, 128, 128, off2_w, off2_b, om2,
                                                        4, 27, 64, 64, 1, 0, 0, 0);

    // ---- pre2 = deform_conv(skip2, om2) (128ch @64x64) ----
    deform_conv_kernel<128, 8><<<dim3(4*64*8), dim3(128), 0, stream>>>(skip2, om2, dcn2_w, dcn2_b,
                                                                       pre2, 4, 64, 64);

    // ---- up2 + refpad2 + conv5x5 on concat[pre2, out1] (256->64) @128x128, IN+relu ----
    conv_generic<5><<<nb(4*64*128*128), 256, 0, stream>>>(pre2, out1, 128, 128, w2, b2, out2,
                                                          4, 64, 128, 128, 2, 1, 1, 0);
    inorm_kernel<<<dim3(256), dim3(256), 0, stream>>>(out2, out2, nullptr, 16384, 1);

    // ---- om1 = conv3x3 zero-pad on concat[out2, skip1] (128->27) @128x128 ----
    conv_generic<3><<<nb(4*27*128*128), 256, 0, stream>>>(out2, skip1, 64, 64, off1_w, off1_b, om1,
                                                          4, 27, 128, 128, 1, 0, 0, 0);

    // ---- pre1 = deform_conv(skip1, om1) (64ch @128x128) ----
    deform_conv_kernel<64, 8><<<dim3(4*128*16), dim3(64), 0, stream>>>(skip1, om1, dcn1_w, dcn1_b,
                                                                       pre1, 4, 128, 128);

    // ---- conv7x7 refpad3 on concat[pre1, out2] (128->3) @128x128, tanh -> d_out ----
    conv_generic<7><<<nb(4*3*128*128), 256, 0, stream>>>(pre1, out2, 64, 64, w3, b3, outp,
                                                         4, 3, 128, 128, 3, 0, 1, 1);

    // ---- offset_sum scalar ----
    abs_sum_kernel<<<dim3(256), dim3(256), 0, stream>>>(om1, 4, 27, 16384, acc + 0);
    abs_sum_kernel<<<dim3(256), dim3(256), 0, stream>>>(om2, 4, 27, 4096, acc + 1);
    finalize_kernel<<<dim3(1), dim3(1), 0, stream>>>(acc, outp + 196608);
}